// Round 7
// baseline (45.159 us; speedup 1.0000x reference)
//
#include <hip/hip_runtime.h>
#include <hip/hip_bf16.h>

#define N_NODES 100000
#define D 128
#define N_EDGES 1000000

typedef float v2f __attribute__((ext_vector_type(2)));
typedef int   v2i __attribute__((ext_vector_type(2)));

// Kernel 1: per-node scores. 8 lanes per node, 8 nodes/wave, one-shot grid.
// Score table interleaved: s2[n] = { z[n].W_src + b , z[n].W_dst }
__global__ void __launch_bounds__(256, 4) node_scores_kernel(
    const float* __restrict__ z, const float* __restrict__ W,
    const float* __restrict__ b, v2f* __restrict__ s2) {
  const int tid  = blockIdx.x * blockDim.x + threadIdx.x;
  const int wave = tid >> 6;         // 0..12499 (exact)
  const int lane = threadIdx.x & 63;
  const int sub  = lane >> 3;        // node within wave (0..7)
  const int l8   = lane & 7;         // lane within 8-lane group
  const int node = wave * 8 + sub;   // N_NODES % 8 == 0 -> no guard

  const float4* zrow = reinterpret_cast<const float4*>(z + (size_t)node * D);
  const float4 z0 = zrow[l8];
  const float4 z1 = zrow[8 + l8];
  const float4 z2 = zrow[16 + l8];
  const float4 z3 = zrow[24 + l8];

  const float4* Wv = reinterpret_cast<const float4*>(W);
  const float4 ws0 = Wv[l8],      ws1 = Wv[8 + l8];
  const float4 ws2 = Wv[16 + l8], ws3 = Wv[24 + l8];
  const float4 wd0 = Wv[32 + l8], wd1 = Wv[40 + l8];
  const float4 wd2 = Wv[48 + l8], wd3 = Wv[56 + l8];

  float a = z0.x * ws0.x + z0.y * ws0.y + z0.z * ws0.z + z0.w * ws0.w
          + z1.x * ws1.x + z1.y * ws1.y + z1.z * ws1.z + z1.w * ws1.w
          + z2.x * ws2.x + z2.y * ws2.y + z2.z * ws2.z + z2.w * ws2.w
          + z3.x * ws3.x + z3.y * ws3.y + z3.z * ws3.z + z3.w * ws3.w;
  float c = z0.x * wd0.x + z0.y * wd0.y + z0.z * wd0.z + z0.w * wd0.w
          + z1.x * wd1.x + z1.y * wd1.y + z1.z * wd1.z + z1.w * wd1.w
          + z2.x * wd2.x + z2.y * wd2.y + z2.z * wd2.z + z2.w * wd2.w
          + z3.x * wd3.x + z3.y * wd3.y + z3.z * wd3.z + z3.w * wd3.w;

  #pragma unroll
  for (int off = 4; off >= 1; off >>= 1) {
    a += __shfl_xor(a, off, 64);
    c += __shfl_xor(c, off, 64);
  }
  if (l8 == 0) {
    v2f st;
    st.x = a + b[0];
    st.y = c;
    s2[node] = st;
  }
}

// Kernel 2: 2 edges/thread; random 4B gathers into the 800KB pair table.
__global__ void __launch_bounds__(256) edge_kernel(
    const int* __restrict__ idx, const float* __restrict__ sp,
    float* __restrict__ out) {
  int t = blockIdx.x * blockDim.x + threadIdx.x;
  if (t * 2 >= N_EDGES) return;
  const v2i sv = __builtin_nontemporal_load(
      reinterpret_cast<const v2i*>(idx) + t);            // src row
  const v2i dv = __builtin_nontemporal_load(
      reinterpret_cast<const v2i*>(idx + N_EDGES) + t);  // dst row

  float l0 = sp[2 * sv.x] + sp[2 * dv.x + 1];
  float l1 = sp[2 * sv.y] + sp[2 * dv.y + 1];

  v2f o;
  o.x = 1.0f / (1.0f + __expf(-l0));
  o.y = 1.0f / (1.0f + __expf(-l1));
  __builtin_nontemporal_store(o, reinterpret_cast<v2f*>(out) + t);
}

extern "C" void kernel_launch(void* const* d_in, const int* in_sizes, int n_in,
                              void* d_out, int out_size, void* d_ws, size_t ws_size,
                              hipStream_t stream) {
  const float* z   = (const float*)d_in[0];
  const int*   idx = (const int*)d_in[1];
  const float* W   = (const float*)d_in[2];
  const float* b   = (const float*)d_in[3];
  float* out = (float*)d_out;
  v2f*   s2  = (v2f*)d_ws;   // N_NODES float2 pairs = 800 KB

  node_scores_kernel<<<N_NODES / 32, 256, 0, stream>>>(z, W, b, s2);

  // DIAGNOSTIC: launch edge_kernel 3x (idempotent) to attribute duration.
  // dur ~= k1 + 3*k2 + overhead. k2-dominant theory -> ~51us; k1-dominant -> ~34us.
  int blocks2 = (N_EDGES / 2 + 255) / 256;  // 1954
  edge_kernel<<<blocks2, 256, 0, stream>>>(idx, (const float*)s2, out);
  edge_kernel<<<blocks2, 256, 0, stream>>>(idx, (const float*)s2, out);
  edge_kernel<<<blocks2, 256, 0, stream>>>(idx, (const float*)s2, out);
}

// Round 8
// 42.334 us; speedup vs baseline: 1.0667x; 1.0667x over previous
//
#include <hip/hip_runtime.h>
#include <hip/hip_bf16.h>

#define N_NODES 100000
#define D 128
#define N_EDGES 1000000

typedef float v2f __attribute__((ext_vector_type(2)));
typedef int   v2i __attribute__((ext_vector_type(2)));

// Kernel 1: per-node scores. 8 lanes per node, 8 nodes/wave, one-shot grid.
// Score table interleaved: s2[n] = { z[n].W_src + b , z[n].W_dst }
__global__ void __launch_bounds__(256, 4) node_scores_kernel(
    const float* __restrict__ z, const float* __restrict__ W,
    const float* __restrict__ b, v2f* __restrict__ s2) {
  const int tid  = blockIdx.x * blockDim.x + threadIdx.x;
  const int wave = tid >> 6;         // 0..12499 (exact)
  const int lane = threadIdx.x & 63;
  const int sub  = lane >> 3;        // node within wave (0..7)
  const int l8   = lane & 7;         // lane within 8-lane group
  const int node = wave * 8 + sub;   // N_NODES % 8 == 0 -> no guard

  const float4* zrow = reinterpret_cast<const float4*>(z + (size_t)node * D);
  const float4 z0 = zrow[l8];
  const float4 z1 = zrow[8 + l8];
  const float4 z2 = zrow[16 + l8];
  const float4 z3 = zrow[24 + l8];

  const float4* Wv = reinterpret_cast<const float4*>(W);
  const float4 ws0 = Wv[l8],      ws1 = Wv[8 + l8];
  const float4 ws2 = Wv[16 + l8], ws3 = Wv[24 + l8];
  const float4 wd0 = Wv[32 + l8], wd1 = Wv[40 + l8];
  const float4 wd2 = Wv[48 + l8], wd3 = Wv[56 + l8];

  float a = z0.x * ws0.x + z0.y * ws0.y + z0.z * ws0.z + z0.w * ws0.w
          + z1.x * ws1.x + z1.y * ws1.y + z1.z * ws1.z + z1.w * ws1.w
          + z2.x * ws2.x + z2.y * ws2.y + z2.z * ws2.z + z2.w * ws2.w
          + z3.x * ws3.x + z3.y * ws3.y + z3.z * ws3.z + z3.w * ws3.w;
  float c = z0.x * wd0.x + z0.y * wd0.y + z0.z * wd0.z + z0.w * wd0.w
          + z1.x * wd1.x + z1.y * wd1.y + z1.z * wd1.z + z1.w * wd1.w
          + z2.x * wd2.x + z2.y * wd2.y + z2.z * wd2.z + z2.w * wd2.w
          + z3.x * wd3.x + z3.y * wd3.y + z3.z * wd3.z + z3.w * wd3.w;

  #pragma unroll
  for (int off = 4; off >= 1; off >>= 1) {
    a += __shfl_xor(a, off, 64);
    c += __shfl_xor(c, off, 64);
  }
  if (l8 == 0) {
    v2f st;
    st.x = a + b[0];
    st.y = c;
    s2[node] = st;
  }
}

// Kernel 2: 2 edges/thread; random 4B gathers into the 800KB pair table.
__global__ void __launch_bounds__(256) edge_kernel(
    const int* __restrict__ idx, const float* __restrict__ sp,
    float* __restrict__ out) {
  int t = blockIdx.x * blockDim.x + threadIdx.x;
  if (t * 2 >= N_EDGES) return;
  const v2i sv = __builtin_nontemporal_load(
      reinterpret_cast<const v2i*>(idx) + t);            // src row
  const v2i dv = __builtin_nontemporal_load(
      reinterpret_cast<const v2i*>(idx + N_EDGES) + t);  // dst row

  float l0 = sp[2 * sv.x] + sp[2 * dv.x + 1];
  float l1 = sp[2 * sv.y] + sp[2 * dv.y + 1];

  v2f o;
  o.x = 1.0f / (1.0f + __expf(-l0));
  o.y = 1.0f / (1.0f + __expf(-l1));
  __builtin_nontemporal_store(o, reinterpret_cast<v2f*>(out) + t);
}

extern "C" void kernel_launch(void* const* d_in, const int* in_sizes, int n_in,
                              void* d_out, int out_size, void* d_ws, size_t ws_size,
                              hipStream_t stream) {
  const float* z   = (const float*)d_in[0];
  const int*   idx = (const int*)d_in[1];
  const float* W   = (const float*)d_in[2];
  const float* b   = (const float*)d_in[3];
  float* out = (float*)d_out;
  v2f*   s2  = (v2f*)d_ws;   // N_NODES float2 pairs = 800 KB

  // DIAGNOSTIC: launch k1 3x (idempotent) to attribute duration.
  // R8 ~= 25.0 + 2*k1 (+2 dispatch overheads).
  node_scores_kernel<<<N_NODES / 32, 256, 0, stream>>>(z, W, b, s2);
  node_scores_kernel<<<N_NODES / 32, 256, 0, stream>>>(z, W, b, s2);
  node_scores_kernel<<<N_NODES / 32, 256, 0, stream>>>(z, W, b, s2);

  int blocks2 = (N_EDGES / 2 + 255) / 256;  // 1954
  edge_kernel<<<blocks2, 256, 0, stream>>>(idx, (const float*)s2, out);
}

// Round 9
// 24.229 us; speedup vs baseline: 1.8638x; 1.7472x over previous
//
#include <hip/hip_runtime.h>
#include <hip/hip_bf16.h>

#define N_NODES 100000
#define D 128
#define N_EDGES 1000000

typedef float v2f __attribute__((ext_vector_type(2)));
typedef int   v2i __attribute__((ext_vector_type(2)));

// Kernel 1: per-node scores. 8 lanes per node, 8 nodes/wave, one-shot grid.
// Packed bf16 table: tbl[n] = bf16(z[n].W_src + b) | bf16(z[n].W_dst) << 16
// -> 4B/node, 400KB total (halves k2's gather line footprint vs float2).
__global__ void __launch_bounds__(256, 4) node_scores_kernel(
    const float* __restrict__ z, const float* __restrict__ W,
    const float* __restrict__ b, unsigned int* __restrict__ tbl) {
  const int tid  = blockIdx.x * blockDim.x + threadIdx.x;
  const int wave = tid >> 6;         // 0..12499 (exact)
  const int lane = threadIdx.x & 63;
  const int sub  = lane >> 3;        // node within wave (0..7)
  const int l8   = lane & 7;         // lane within 8-lane group
  const int node = wave * 8 + sub;   // N_NODES % 8 == 0 -> no guard

  const float4* zrow = reinterpret_cast<const float4*>(z + (size_t)node * D);
  const float4 z0 = zrow[l8];
  const float4 z1 = zrow[8 + l8];
  const float4 z2 = zrow[16 + l8];
  const float4 z3 = zrow[24 + l8];

  const float4* Wv = reinterpret_cast<const float4*>(W);
  const float4 ws0 = Wv[l8],      ws1 = Wv[8 + l8];
  const float4 ws2 = Wv[16 + l8], ws3 = Wv[24 + l8];
  const float4 wd0 = Wv[32 + l8], wd1 = Wv[40 + l8];
  const float4 wd2 = Wv[48 + l8], wd3 = Wv[56 + l8];

  float a = z0.x * ws0.x + z0.y * ws0.y + z0.z * ws0.z + z0.w * ws0.w
          + z1.x * ws1.x + z1.y * ws1.y + z1.z * ws1.z + z1.w * ws1.w
          + z2.x * ws2.x + z2.y * ws2.y + z2.z * ws2.z + z2.w * ws2.w
          + z3.x * ws3.x + z3.y * ws3.y + z3.z * ws3.z + z3.w * ws3.w;
  float c = z0.x * wd0.x + z0.y * wd0.y + z0.z * wd0.z + z0.w * wd0.w
          + z1.x * wd1.x + z1.y * wd1.y + z1.z * wd1.z + z1.w * wd1.w
          + z2.x * wd2.x + z2.y * wd2.y + z2.z * wd2.z + z2.w * wd2.w
          + z3.x * wd3.x + z3.y * wd3.y + z3.z * wd3.z + z3.w * wd3.w;

  #pragma unroll
  for (int off = 4; off >= 1; off >>= 1) {
    a += __shfl_xor(a, off, 64);
    c += __shfl_xor(c, off, 64);
  }
  if (l8 == 0) {
    const unsigned int ha =
        (unsigned int)__bfloat16_as_ushort(__float2bfloat16(a + b[0]));
    const unsigned int hc =
        (unsigned int)__bfloat16_as_ushort(__float2bfloat16(c));
    tbl[node] = ha | (hc << 16);
  }
}

// Kernel 2: 2 edges/thread; random 4B gathers into the 400KB packed table.
// Unpack: src score = lo16 << 16 (as f32), dst score = hi16 masked (as f32).
__global__ void __launch_bounds__(256) edge_kernel(
    const int* __restrict__ idx, const unsigned int* __restrict__ tbl,
    float* __restrict__ out) {
  int t = blockIdx.x * blockDim.x + threadIdx.x;
  if (t * 2 >= N_EDGES) return;
  const v2i sv = __builtin_nontemporal_load(
      reinterpret_cast<const v2i*>(idx) + t);            // src row
  const v2i dv = __builtin_nontemporal_load(
      reinterpret_cast<const v2i*>(idx + N_EDGES) + t);  // dst row

  const unsigned int ua0 = tbl[sv.x], ub0 = tbl[dv.x];
  const unsigned int ua1 = tbl[sv.y], ub1 = tbl[dv.y];

  float l0 = __uint_as_float(ua0 << 16) + __uint_as_float(ub0 & 0xFFFF0000u);
  float l1 = __uint_as_float(ua1 << 16) + __uint_as_float(ub1 & 0xFFFF0000u);

  v2f o;
  o.x = 1.0f / (1.0f + __expf(-l0));
  o.y = 1.0f / (1.0f + __expf(-l1));
  __builtin_nontemporal_store(o, reinterpret_cast<v2f*>(out) + t);
}

extern "C" void kernel_launch(void* const* d_in, const int* in_sizes, int n_in,
                              void* d_out, int out_size, void* d_ws, size_t ws_size,
                              hipStream_t stream) {
  const float* z   = (const float*)d_in[0];
  const int*   idx = (const int*)d_in[1];
  const float* W   = (const float*)d_in[2];
  const float* b   = (const float*)d_in[3];
  float* out = (float*)d_out;
  unsigned int* tbl = (unsigned int*)d_ws;   // N_NODES packed bf16 pairs = 400 KB

  node_scores_kernel<<<N_NODES / 32, 256, 0, stream>>>(z, W, b, tbl);

  int blocks2 = (N_EDGES / 2 + 255) / 256;  // 1954
  edge_kernel<<<blocks2, 256, 0, stream>>>(idx, tbl, out);
}